// Round 12
// baseline (907.237 us; speedup 1.0000x reference)
//
#include <hip/hip_runtime.h>
#include <hip/hip_bf16.h>

// Problem constants
#define NB 64    // batch
#define TT 512   // timesteps
#define HH 512   // hidden
#define DD 512   // input dim

typedef __attribute__((ext_vector_type(8))) __bf16 bf16x8;
typedef __attribute__((ext_vector_type(4))) float f32x4;

__device__ __forceinline__ unsigned short f2bf_rn(float f) {
    union { float f; unsigned u; } v; v.f = f;
    unsigned r = v.u + 0x7FFFu + ((v.u >> 16) & 1u);
    return (unsigned short)(r >> 16);
}
__device__ __forceinline__ float bf2f(unsigned short s) {
    union { unsigned u; float f; } v; v.u = ((unsigned)s) << 16;
    return v.f;
}

// ---------------------------------------------------------------------------
// Kernel 1: Wt[n][k]   = bf16_hi(Wx[k][n])   (n in [0,512), k in [0,512))
//           Wt[n][512+k] = bf16_lo(Wx[k][n])
// ---------------------------------------------------------------------------
__global__ __launch_bounds__(256) void wt_kernel(const float* __restrict__ Wx,
                                                 unsigned short* __restrict__ Wt) {
    const int bk = blockIdx.x >> 3, bn = blockIdx.x & 7;
    const int k0 = bk * 64, n0 = bn * 64;
    __shared__ float tile[64][65];
    const int t = threadIdx.x;
    const int kr = t >> 2, seg = t & 3;
    const float4* src = (const float4*)&Wx[(k0 + kr) * HH + n0 + seg * 16];
    float4 a = src[0], b = src[1], c = src[2], d = src[3];
    float vv[16];
    *(float4*)&vv[0] = a; *(float4*)&vv[4] = b; *(float4*)&vv[8] = c; *(float4*)&vv[12] = d;
#pragma unroll
    for (int q = 0; q < 16; ++q) tile[kr][seg * 16 + q] = vv[q];
    __syncthreads();
    const int nr = t >> 2;
    unsigned hu[8], lu[8];
#pragma unroll
    for (int i = 0; i < 8; ++i) {
        float f0 = tile[seg * 16 + 2 * i + 0][nr];
        float f1 = tile[seg * 16 + 2 * i + 1][nr];
        unsigned short h0 = f2bf_rn(f0); unsigned short l0 = f2bf_rn(f0 - bf2f(h0));
        unsigned short h1 = f2bf_rn(f1); unsigned short l1 = f2bf_rn(f1 - bf2f(h1));
        hu[i] = (unsigned)h0 | ((unsigned)h1 << 16);
        lu[i] = (unsigned)l0 | ((unsigned)l1 << 16);
    }
    unsigned short* dh = &Wt[(n0 + nr) * 1024 + k0 + seg * 16];
    unsigned short* dl = dh + 512;
    ((uint4*)dh)[0] = make_uint4(hu[0], hu[1], hu[2], hu[3]);
    ((uint4*)dh)[1] = make_uint4(hu[4], hu[5], hu[6], hu[7]);
    ((uint4*)dl)[0] = make_uint4(lu[0], lu[1], lu[2], lu[3]);
    ((uint4*)dl)[1] = make_uint4(lu[4], lu[5], lu[6], lu[7]);
}

// ---------------------------------------------------------------------------
// Kernel 2: projection GEMM  out[i][j] = sum_k x[i][k]*Wx[k][j] + b[j]
// split-bf16 (hi*hi + hi*lo + lo*hi) via MFMA, fp32-accurate.
// ---------------------------------------------------------------------------
#define LDA 72
__global__ __launch_bounds__(256) void proj_kernel(const float* __restrict__ x,
                                                   const unsigned short* __restrict__ Wt,
                                                   const float* __restrict__ bias,
                                                   float* __restrict__ out) {
    __shared__ __align__(16) unsigned short a_hi[64 * LDA];
    __shared__ __align__(16) unsigned short a_lo[64 * LDA];
    __shared__ __align__(16) unsigned short b_hi[64 * LDA];
    __shared__ __align__(16) unsigned short b_lo[64 * LDA];

    const int bx = blockIdx.x;
    const int i0 = (bx >> 3) * 64;
    const int n0 = (bx & 7) * 64;
    const int t = threadIdx.x;
    const int row = t >> 2, seg = t & 3;
    const int lane = t & 63, wid = t >> 6;
    const int wm = (wid >> 1) * 32, wn = (wid & 1) * 32;
    const int fr = lane & 15;

    f32x4 acc00 = {0.f, 0.f, 0.f, 0.f}, acc01 = acc00, acc10 = acc00, acc11 = acc00;

    for (int kc = 0; kc < 8; ++kc) {
        __syncthreads();
        {
            const float4* src = (const float4*)&x[(i0 + row) * DD + kc * 64 + seg * 16];
            float4 a = src[0], b = src[1], c = src[2], d = src[3];
            float vv[16];
            *(float4*)&vv[0] = a; *(float4*)&vv[4] = b; *(float4*)&vv[8] = c; *(float4*)&vv[12] = d;
            unsigned hu[8], lu[8];
#pragma unroll
            for (int i = 0; i < 8; ++i) {
                unsigned short h0 = f2bf_rn(vv[2 * i]); unsigned short l0 = f2bf_rn(vv[2 * i] - bf2f(h0));
                unsigned short h1 = f2bf_rn(vv[2 * i + 1]); unsigned short l1 = f2bf_rn(vv[2 * i + 1] - bf2f(h1));
                hu[i] = (unsigned)h0 | ((unsigned)h1 << 16);
                lu[i] = (unsigned)l0 | ((unsigned)l1 << 16);
            }
            uint4* dh = (uint4*)&a_hi[row * LDA + seg * 16];
            uint4* dl = (uint4*)&a_lo[row * LDA + seg * 16];
            dh[0] = make_uint4(hu[0], hu[1], hu[2], hu[3]);
            dh[1] = make_uint4(hu[4], hu[5], hu[6], hu[7]);
            dl[0] = make_uint4(lu[0], lu[1], lu[2], lu[3]);
            dl[1] = make_uint4(lu[4], lu[5], lu[6], lu[7]);
        }
        {
            const uint4* sh = (const uint4*)&Wt[(n0 + row) * 1024 + kc * 64 + seg * 16];
            const uint4* sl = (const uint4*)&Wt[(n0 + row) * 1024 + 512 + kc * 64 + seg * 16];
            uint4 h0v = sh[0], h1v = sh[1], l0v = sl[0], l1v = sl[1];
            uint4* dh = (uint4*)&b_hi[row * LDA + seg * 16];
            uint4* dl = (uint4*)&b_lo[row * LDA + seg * 16];
            dh[0] = h0v; dh[1] = h1v; dl[0] = l0v; dl[1] = l1v;
        }
        __syncthreads();
#pragma unroll
        for (int s = 0; s < 2; ++s) {
            const int ko = s * 32 + (lane >> 4) * 8;
            bf16x8 ah0 = *(const bf16x8*)&a_hi[(wm + fr) * LDA + ko];
            bf16x8 ah1 = *(const bf16x8*)&a_hi[(wm + 16 + fr) * LDA + ko];
            bf16x8 al0 = *(const bf16x8*)&a_lo[(wm + fr) * LDA + ko];
            bf16x8 al1 = *(const bf16x8*)&a_lo[(wm + 16 + fr) * LDA + ko];
            bf16x8 bh0 = *(const bf16x8*)&b_hi[(wn + fr) * LDA + ko];
            bf16x8 bh1 = *(const bf16x8*)&b_hi[(wn + 16 + fr) * LDA + ko];
            bf16x8 bl0 = *(const bf16x8*)&b_lo[(wn + fr) * LDA + ko];
            bf16x8 bl1 = *(const bf16x8*)&b_lo[(wn + 16 + fr) * LDA + ko];
            acc00 = __builtin_amdgcn_mfma_f32_16x16x32_bf16(ah0, bh0, acc00, 0, 0, 0);
            acc00 = __builtin_amdgcn_mfma_f32_16x16x32_bf16(ah0, bl0, acc00, 0, 0, 0);
            acc00 = __builtin_amdgcn_mfma_f32_16x16x32_bf16(al0, bh0, acc00, 0, 0, 0);
            acc01 = __builtin_amdgcn_mfma_f32_16x16x32_bf16(ah0, bh1, acc01, 0, 0, 0);
            acc01 = __builtin_amdgcn_mfma_f32_16x16x32_bf16(ah0, bl1, acc01, 0, 0, 0);
            acc01 = __builtin_amdgcn_mfma_f32_16x16x32_bf16(al0, bh1, acc01, 0, 0, 0);
            acc10 = __builtin_amdgcn_mfma_f32_16x16x32_bf16(ah1, bh0, acc10, 0, 0, 0);
            acc10 = __builtin_amdgcn_mfma_f32_16x16x32_bf16(ah1, bl0, acc10, 0, 0, 0);
            acc10 = __builtin_amdgcn_mfma_f32_16x16x32_bf16(al1, bh0, acc10, 0, 0, 0);
            acc11 = __builtin_amdgcn_mfma_f32_16x16x32_bf16(ah1, bh1, acc11, 0, 0, 0);
            acc11 = __builtin_amdgcn_mfma_f32_16x16x32_bf16(ah1, bl1, acc11, 0, 0, 0);
            acc11 = __builtin_amdgcn_mfma_f32_16x16x32_bf16(al1, bh1, acc11, 0, 0, 0);
        }
    }
    const float bc0 = bias[n0 + wn + fr];
    const float bc1 = bias[n0 + wn + 16 + fr];
#pragma unroll
    for (int r = 0; r < 4; ++r) {
        int rw0 = i0 + wm + (lane >> 4) * 4 + r;
        int rw1 = rw0 + 16;
        out[rw0 * HH + n0 + wn + fr]      = acc00[r] + bc0;
        out[rw0 * HH + n0 + wn + 16 + fr] = acc01[r] + bc1;
        out[rw1 * HH + n0 + wn + fr]      = acc10[r] + bc0;
        out[rw1 * HH + n0 + wn + 16 + fr] = acc11[r] + bc1;
    }
}

// ---------------------------------------------------------------------------
// Kernel 3: recurrence — EARLY reduced ships via per-cc compute->shfl->ship.
// 256 blocks x 512 threads. block b: batch g=b&63, k-slice s=b>>6.
// Lane l: kg=l>>4 (k-subgroup), li=l&15; wave w covers columns cidx=16w+li.
//
// Weights are loaded in PROCESSING ORDER q: column-group cc=(s+1+q)&3, so
// the unrolled q-loop uses only compile-time indices (no runtime-indexed
// arrays -> no scratch; fixes round-11's p[ccq]/p[s] rule-#20 defect).
// Per q in 0..2: 32 FMAs -> 2 shfl_xor k-reduce -> lane-group kg==q+1 ships
// its reduced tagged word IMMEDIATELY (~T+150/250/350 vs T+950 in round 8).
// Arrival at the consumer (ship + L~2400cy visibility) then overlaps the
// consumer's own compute+poll phase instead of being serially exposed.
// Own group (q=3, cc=s) computed last; finisher lanes (kg=0) poll 3 remote
// words for column jf, sum + xw, tanh, publish. One barrier/step.
// Traffic: 384 reduced stores/block/step (round-8 level, NOT round-10's 4x).
//
// Safety: identical tagged-word protocol (8B single-copy-atomic, exact tag,
// 2-slot dbuf). Sender s' ships column-group (s'+kg)&3 at plane
// idx = s' - (s' > owner): over the 3 peer slices this covers planes
// {0,1,2} of each owner bijectively. Per-batch all-to-all consumption =>
// +-1-step lockstep => slot reuse at t+2 cannot race an unconsumed t.
// Ships precede polls in program order => no intra-wave deadlock.
// ---------------------------------------------------------------------------
__global__ __launch_bounds__(512, 2) void rec_kernel(const float* __restrict__ h0,
                                                     const float* __restrict__ Wh,
                                                     float* __restrict__ out,
                                                     unsigned long long* __restrict__ pbuf) {
    const int b = blockIdx.x;
    const int g = b & 63;              // batch
    const int s = b >> 6;              // k-slice
    const int tid = threadIdx.x;
    const int wave = tid >> 6, lane = tid & 63;
    const int kg = lane >> 4;          // k-subgroup (within wave)
    const int li = lane & 15;
    const int cidx = wave * 16 + li;   // column index within a 128-col group
    const bool fin = (kg == 0);        // finisher lanes (16 per wave)
    const int jf = cidx + 128 * s;     // finisher's global column

    // ship-lane constants (kg=1..3): ships processing-order q = kg-1,
    // i.e. column-group cc = (s+kg)&3, global column jship, plane sidx.
    const int ccs = (s + kg) & 3;
    const int jship = cidx + 128 * ccs;
    const int sidx = s - (s > ccs ? 1 : 0);

    // w[q][r] = Wh[128s + 32kg + r][cidx + 128*((s+1+q)&3)]  (own group q=3)
    float w[4][32];
#pragma unroll
    for (int q = 0; q < 4; ++q) {
        const int cc = (s + 1 + q) & 3;
#pragma unroll
        for (int r = 0; r < 32; ++r)
            w[q][r] = Wh[(s * 128 + kg * 32 + r) * HH + cidx + 128 * cc];
    }

    // h partition: hpart[slot][kg*36+i] = h[32kg+i]  (pad 36 -> disjoint banks)
    __shared__ float hpart[2][4 * 36];
    if (tid < 128) hpart[0][(tid >> 5) * 36 + (tid & 31)] = h0[g * HH + s * 128 + tid];

    float xw = fin ? out[(g * TT + 0) * HH + jf] : 0.f;
    __syncthreads();

#pragma unroll 1
    for (int t = 0; t < TT; ++t) {
        const int slot = t & 1;
        const unsigned tg = (unsigned)(t + 1);
        const unsigned mbase = ((unsigned)slot * NB + (unsigned)g) * 3u;

        // ---- local h window (16-lane-group broadcast; disjoint banks) ----
        float4 hv[8];
        const float4* h4 = (const float4*)&hpart[slot][kg * 36];
#pragma unroll
        for (int r4 = 0; r4 < 8; ++r4) hv[r4] = h4[r4];

        // ---- per-cc: compute -> in-wave reduce -> ship (remote groups
        //      first, each shipped the moment it is reduced) ----
        float pown = 0.f;
#pragma unroll
        for (int q = 0; q < 4; ++q) {
            float a0 = 0.f, a1 = 0.f, a2 = 0.f, a3 = 0.f;
#pragma unroll
            for (int r4 = 0; r4 < 8; ++r4) {
                float4 h = hv[r4];
                a0 = fmaf(w[q][4 * r4 + 0], h.x, a0);
                a1 = fmaf(w[q][4 * r4 + 1], h.y, a1);
                a2 = fmaf(w[q][4 * r4 + 2], h.z, a2);
                a3 = fmaf(w[q][4 * r4 + 3], h.w, a3);
            }
            float p = (a0 + a1) + (a2 + a3);
            p += __shfl_xor(p, 16, 64);
            p += __shfl_xor(p, 32, 64);
            if (q < 3) {
                if (kg == q + 1) {   // this lane-group's assigned remote group
                    unsigned long long pv = ((unsigned long long)tg << 32) |
                                            (unsigned long long)__float_as_uint(p);
                    __hip_atomic_store(&pbuf[(mbase + (unsigned)sidx) * HH + (unsigned)jship],
                                       pv, __ATOMIC_RELAXED, __HIP_MEMORY_SCOPE_AGENT);
                }
            } else {
                pown = p;            // own group (cc == s)
            }
        }

        // ---- finisher: poll 3 remote words, finish column jf ----
        if (fin) {
            float xwn = (t + 1 < TT) ? out[(g * TT + t + 1) * HH + jf] : 0.f;
            const unsigned long long* a0p = &pbuf[mbase * HH + (unsigned)jf];
            const unsigned long long* a1p = a0p + HH;
            const unsigned long long* a2p = a1p + HH;
            unsigned long long v0, v1, v2;
            do {
                v0 = __hip_atomic_load(a0p, __ATOMIC_RELAXED, __HIP_MEMORY_SCOPE_AGENT);
                v1 = __hip_atomic_load(a1p, __ATOMIC_RELAXED, __HIP_MEMORY_SCOPE_AGENT);
                v2 = __hip_atomic_load(a2p, __ATOMIC_RELAXED, __HIP_MEMORY_SCOPE_AGENT);
            } while ((unsigned)(v0 >> 32) != tg || (unsigned)(v1 >> 32) != tg ||
                     (unsigned)(v2 >> 32) != tg);
            float sum = pown + __uint_as_float((unsigned)v0) + __uint_as_float((unsigned)v1) +
                        __uint_as_float((unsigned)v2) + xw;
            // tanh via exp: exact at saturation, ~1e-7 rel error
            float hn = 1.f - 2.f / (__expf(2.f * sum) + 1.f);
            out[(g * TT + t) * HH + jf] = hn;
            hpart[slot ^ 1][(cidx >> 5) * 36 + (cidx & 31)] = hn;
            xw = xwn;
        }
        __syncthreads();   // hpart[slot^1] complete before next step's reads
    }
}

// ---------------------------------------------------------------------------
extern "C" void kernel_launch(void* const* d_in, const int* in_sizes, int n_in,
                              void* d_out, int out_size, void* d_ws, size_t ws_size,
                              hipStream_t stream) {
    (void)in_sizes; (void)n_in; (void)out_size; (void)ws_size;
    const float* x  = (const float*)d_in[0];
    const float* h0 = (const float*)d_in[1];
    const float* Wx = (const float*)d_in[2];
    const float* Wh = (const float*)d_in[3];
    const float* bv = (const float*)d_in[4];
    float* out = (float*)d_out;

    // workspace layout: mailbox [2][NB][3][HH] 8B words, then Wt
    const size_t PBUF_BYTES = 2ull * NB * 3 * HH * sizeof(unsigned long long); // 1.5 MiB
    unsigned long long* pbuf = (unsigned long long*)d_ws;
    unsigned short* Wt = (unsigned short*)((char*)d_ws + PBUF_BYTES);          // +1 MiB

    // zero mailbox tags (tag 0 never matches any expected tag >= 1)
    hipMemsetAsync(pbuf, 0, PBUF_BYTES, stream);

    // 1) split+transpose Wx -> Wt (bf16 hi|lo, B^T layout)
    wt_kernel<<<64, 256, 0, stream>>>(Wx, Wt);

    // 2) projection GEMM: d_out = x @ Wx + b  (split-bf16 MFMA, fp32-accurate)
    proj_kernel<<<(32768 / 64) * (HH / 64), 256, 0, stream>>>(x, Wt, bv, out);

    // 3) sequential recurrence, early reduced ships
    rec_kernel<<<NB * 4, 512, 0, stream>>>(h0, Wh, out, pbuf);
}

// Round 14
// 826.089 us; speedup vs baseline: 1.0982x; 1.0982x over previous
//
#include <hip/hip_runtime.h>
#include <hip/hip_bf16.h>

// Problem constants
#define NB 64    // batch
#define TT 512   // timesteps
#define HH 512   // hidden
#define DD 512   // input dim

typedef __attribute__((ext_vector_type(8))) __bf16 bf16x8;
typedef __attribute__((ext_vector_type(4))) float f32x4;

__device__ __forceinline__ unsigned short f2bf_rn(float f) {
    union { float f; unsigned u; } v; v.f = f;
    unsigned r = v.u + 0x7FFFu + ((v.u >> 16) & 1u);
    return (unsigned short)(r >> 16);
}
__device__ __forceinline__ float bf2f(unsigned short s) {
    union { unsigned u; float f; } v; v.u = ((unsigned)s) << 16;
    return v.f;
}

// ---------------------------------------------------------------------------
// Kernel 1: Wt[n][k]   = bf16_hi(Wx[k][n])   (n in [0,512), k in [0,512))
//           Wt[n][512+k] = bf16_lo(Wx[k][n])
// ---------------------------------------------------------------------------
__global__ __launch_bounds__(256) void wt_kernel(const float* __restrict__ Wx,
                                                 unsigned short* __restrict__ Wt) {
    const int bk = blockIdx.x >> 3, bn = blockIdx.x & 7;
    const int k0 = bk * 64, n0 = bn * 64;
    __shared__ float tile[64][65];
    const int t = threadIdx.x;
    const int kr = t >> 2, seg = t & 3;
    const float4* src = (const float4*)&Wx[(k0 + kr) * HH + n0 + seg * 16];
    float4 a = src[0], b = src[1], c = src[2], d = src[3];
    float vv[16];
    *(float4*)&vv[0] = a; *(float4*)&vv[4] = b; *(float4*)&vv[8] = c; *(float4*)&vv[12] = d;
#pragma unroll
    for (int q = 0; q < 16; ++q) tile[kr][seg * 16 + q] = vv[q];
    __syncthreads();
    const int nr = t >> 2;
    unsigned hu[8], lu[8];
#pragma unroll
    for (int i = 0; i < 8; ++i) {
        float f0 = tile[seg * 16 + 2 * i + 0][nr];
        float f1 = tile[seg * 16 + 2 * i + 1][nr];
        unsigned short h0 = f2bf_rn(f0); unsigned short l0 = f2bf_rn(f0 - bf2f(h0));
        unsigned short h1 = f2bf_rn(f1); unsigned short l1 = f2bf_rn(f1 - bf2f(h1));
        hu[i] = (unsigned)h0 | ((unsigned)h1 << 16);
        lu[i] = (unsigned)l0 | ((unsigned)l1 << 16);
    }
    unsigned short* dh = &Wt[(n0 + nr) * 1024 + k0 + seg * 16];
    unsigned short* dl = dh + 512;
    ((uint4*)dh)[0] = make_uint4(hu[0], hu[1], hu[2], hu[3]);
    ((uint4*)dh)[1] = make_uint4(hu[4], hu[5], hu[6], hu[7]);
    ((uint4*)dl)[0] = make_uint4(lu[0], lu[1], lu[2], lu[3]);
    ((uint4*)dl)[1] = make_uint4(lu[4], lu[5], lu[6], lu[7]);
}

// ---------------------------------------------------------------------------
// Kernel 2: projection GEMM  out[i][j] = sum_k x[i][k]*Wx[k][j] + b[j]
// split-bf16 (hi*hi + hi*lo + lo*hi) via MFMA, fp32-accurate.
// ---------------------------------------------------------------------------
#define LDA 72
__global__ __launch_bounds__(256) void proj_kernel(const float* __restrict__ x,
                                                   const unsigned short* __restrict__ Wt,
                                                   const float* __restrict__ bias,
                                                   float* __restrict__ out) {
    __shared__ __align__(16) unsigned short a_hi[64 * LDA];
    __shared__ __align__(16) unsigned short a_lo[64 * LDA];
    __shared__ __align__(16) unsigned short b_hi[64 * LDA];
    __shared__ __align__(16) unsigned short b_lo[64 * LDA];

    const int bx = blockIdx.x;
    const int i0 = (bx >> 3) * 64;
    const int n0 = (bx & 7) * 64;
    const int t = threadIdx.x;
    const int row = t >> 2, seg = t & 3;
    const int lane = t & 63, wid = t >> 6;
    const int wm = (wid >> 1) * 32, wn = (wid & 1) * 32;
    const int fr = lane & 15;

    f32x4 acc00 = {0.f, 0.f, 0.f, 0.f}, acc01 = acc00, acc10 = acc00, acc11 = acc00;

    for (int kc = 0; kc < 8; ++kc) {
        __syncthreads();
        {
            const float4* src = (const float4*)&x[(i0 + row) * DD + kc * 64 + seg * 16];
            float4 a = src[0], b = src[1], c = src[2], d = src[3];
            float vv[16];
            *(float4*)&vv[0] = a; *(float4*)&vv[4] = b; *(float4*)&vv[8] = c; *(float4*)&vv[12] = d;
            unsigned hu[8], lu[8];
#pragma unroll
            for (int i = 0; i < 8; ++i) {
                unsigned short h0 = f2bf_rn(vv[2 * i]); unsigned short l0 = f2bf_rn(vv[2 * i] - bf2f(h0));
                unsigned short h1 = f2bf_rn(vv[2 * i + 1]); unsigned short l1 = f2bf_rn(vv[2 * i + 1] - bf2f(h1));
                hu[i] = (unsigned)h0 | ((unsigned)h1 << 16);
                lu[i] = (unsigned)l0 | ((unsigned)l1 << 16);
            }
            uint4* dh = (uint4*)&a_hi[row * LDA + seg * 16];
            uint4* dl = (uint4*)&a_lo[row * LDA + seg * 16];
            dh[0] = make_uint4(hu[0], hu[1], hu[2], hu[3]);
            dh[1] = make_uint4(hu[4], hu[5], hu[6], hu[7]);
            dl[0] = make_uint4(lu[0], lu[1], lu[2], lu[3]);
            dl[1] = make_uint4(lu[4], lu[5], lu[6], lu[7]);
        }
        {
            const uint4* sh = (const uint4*)&Wt[(n0 + row) * 1024 + kc * 64 + seg * 16];
            const uint4* sl = (const uint4*)&Wt[(n0 + row) * 1024 + 512 + kc * 64 + seg * 16];
            uint4 h0v = sh[0], h1v = sh[1], l0v = sl[0], l1v = sl[1];
            uint4* dh = (uint4*)&b_hi[row * LDA + seg * 16];
            uint4* dl = (uint4*)&b_lo[row * LDA + seg * 16];
            dh[0] = h0v; dh[1] = h1v; dl[0] = l0v; dl[1] = l1v;
        }
        __syncthreads();
#pragma unroll
        for (int s = 0; s < 2; ++s) {
            const int ko = s * 32 + (lane >> 4) * 8;
            bf16x8 ah0 = *(const bf16x8*)&a_hi[(wm + fr) * LDA + ko];
            bf16x8 ah1 = *(const bf16x8*)&a_hi[(wm + 16 + fr) * LDA + ko];
            bf16x8 al0 = *(const bf16x8*)&a_lo[(wm + fr) * LDA + ko];
            bf16x8 al1 = *(const bf16x8*)&a_lo[(wm + 16 + fr) * LDA + ko];
            bf16x8 bh0 = *(const bf16x8*)&b_hi[(wn + fr) * LDA + ko];
            bf16x8 bh1 = *(const bf16x8*)&b_hi[(wn + 16 + fr) * LDA + ko];
            bf16x8 bl0 = *(const bf16x8*)&b_lo[(wn + fr) * LDA + ko];
            bf16x8 bl1 = *(const bf16x8*)&b_lo[(wn + 16 + fr) * LDA + ko];
            acc00 = __builtin_amdgcn_mfma_f32_16x16x32_bf16(ah0, bh0, acc00, 0, 0, 0);
            acc00 = __builtin_amdgcn_mfma_f32_16x16x32_bf16(ah0, bl0, acc00, 0, 0, 0);
            acc00 = __builtin_amdgcn_mfma_f32_16x16x32_bf16(al0, bh0, acc00, 0, 0, 0);
            acc01 = __builtin_amdgcn_mfma_f32_16x16x32_bf16(ah0, bh1, acc01, 0, 0, 0);
            acc01 = __builtin_amdgcn_mfma_f32_16x16x32_bf16(ah0, bl1, acc01, 0, 0, 0);
            acc01 = __builtin_amdgcn_mfma_f32_16x16x32_bf16(al0, bh1, acc01, 0, 0, 0);
            acc10 = __builtin_amdgcn_mfma_f32_16x16x32_bf16(ah1, bh0, acc10, 0, 0, 0);
            acc10 = __builtin_amdgcn_mfma_f32_16x16x32_bf16(ah1, bl0, acc10, 0, 0, 0);
            acc10 = __builtin_amdgcn_mfma_f32_16x16x32_bf16(al1, bh0, acc10, 0, 0, 0);
            acc11 = __builtin_amdgcn_mfma_f32_16x16x32_bf16(ah1, bh1, acc11, 0, 0, 0);
            acc11 = __builtin_amdgcn_mfma_f32_16x16x32_bf16(ah1, bl1, acc11, 0, 0, 0);
            acc11 = __builtin_amdgcn_mfma_f32_16x16x32_bf16(al1, bh1, acc11, 0, 0, 0);
        }
    }
    const float bc0 = bias[n0 + wn + fr];
    const float bc1 = bias[n0 + wn + 16 + fr];
#pragma unroll
    for (int r = 0; r < 4; ++r) {
        int rw0 = i0 + wm + (lane >> 4) * 4 + r;
        int rw1 = rw0 + 16;
        out[rw0 * HH + n0 + wn + fr]      = acc00[r] + bc0;
        out[rw0 * HH + n0 + wn + 16 + fr] = acc01[r] + bc1;
        out[rw1 * HH + n0 + wn + fr]      = acc10[r] + bc0;
        out[rw1 * HH + n0 + wn + 16 + fr] = acc11[r] + bc1;
    }
}

// ---------------------------------------------------------------------------
// Kernel 3: recurrence — round-5 structure (best measured: rec 785 µs) with
// the ONE proven residual fix: conflict-free intra-block reduce layout.
// (identical to the round-13 submission; that bench died to an infra
// failure before execution, so this resubmission obtains its measurement)
// 256 blocks x 512 threads. block b: batch g=b&63, k-slice s=b>>6
// (k in [128s, 128s+128) of Wh, ALL 512 columns).
//
// Thread (kg=tid>>7, c=tid&127): computes cols {c,c+128,c+256,c+384} over
// k-sub-range [128s+32kg, +32). 8 broadcast ds_read_b128 per wave.
//
// Intra-block k-reduce: OLD red4[kg][4c+cc] (finisher reads lane-stride 16B
// -> 8-way bank conflict, SQ_LDS_BANK_CONFLICT=2.5e7/dispatch measured r8).
// NEW red[kg][cc][c]: writer stores its 4 partials at red[kg][cc][c]
// (4x ds_write_b32, lane-consecutive in c); finisher of col jf=c+128kg sums
// red[q][kg][c] over q (4x ds_read_b32, lane-consecutive). Zero conflicts,
// identical math, identical protocol and traffic.
//
// Cross-block: non-owner ships ONE tagged {tag=t+1, partial} 8B word to the
// column-owner block's mailbox; owner polls its 3 remote words, adds xw,
// tanh, publishes hsl (dbuf) + out. Two barriers per step.
// Safety: 8B single-copy-atomic words, exact tag, 2-slot dbuf; block S
// overwrites a slot at iter t+2 only after polling tag-(t+2) words from
// every peer K, which K ships only after its iter-t end barrier, which is
// after K consumed S's tag-(t+1) word. No race. (Protocol unchanged from
// rounds 5/8 which ran clean across many dispatches.)
// ---------------------------------------------------------------------------
__global__ __launch_bounds__(512, 2) void rec_kernel(const float* __restrict__ h0,
                                                     const float* __restrict__ Wh,
                                                     float* __restrict__ out,
                                                     unsigned long long* __restrict__ pbuf) {
    const int b = blockIdx.x;
    const int g = b & 63;            // batch
    const int s = b >> 6;            // k-slice
    const int tid = threadIdx.x;
    const int c = tid & 127;         // column base
    const int kg = tid >> 7;         // k-subgroup / finisher col-group (wave-uniform)
    const int jf = c + 128 * kg;     // this thread's finisher column
    const bool isOwner = (kg == s);  // finisher col belongs to this block's slice
    const int idx = s - (s > kg ? 1 : 0);  // sender position among col-jf's 3 remotes

    // w[cc][r] = Wh[128s + 32kg + r][c + 128cc]  (coalesced on c)
    float w[4][32];
#pragma unroll
    for (int r = 0; r < 32; ++r) {
        const float* row = &Wh[(s * 128 + kg * 32 + r) * HH + c];
#pragma unroll
        for (int cc = 0; cc < 4; ++cc) w[cc][r] = row[128 * cc];
    }

    __shared__ float hsl[2][128];       // this block's own h slice (dbuf)
    __shared__ float red[4][4][128];    // [writer kg][cc][c] — conflict-free
    if (tid < 128) hsl[0][tid] = h0[g * HH + s * 128 + tid];

    float xw = isOwner ? out[(g * TT + 0) * HH + jf] : 0.f;
    __syncthreads();

#pragma unroll 1
    for (int t = 0; t < TT; ++t) {
        const int slot = t & 1;
        const unsigned tg = (unsigned)(t + 1);

        // ---- FMA: 8 broadcast b128 h-reads, 4 independent 32-deep chains ----
        const float4* h4 = (const float4*)&hsl[slot][kg * 32];
        float p0 = 0.f, p1 = 0.f, p2 = 0.f, p3 = 0.f;
#pragma unroll
        for (int r4 = 0; r4 < 8; ++r4) {
            float4 hv = h4[r4];
            p0 = fmaf(w[0][4 * r4 + 0], hv.x, p0);
            p0 = fmaf(w[0][4 * r4 + 1], hv.y, p0);
            p0 = fmaf(w[0][4 * r4 + 2], hv.z, p0);
            p0 = fmaf(w[0][4 * r4 + 3], hv.w, p0);
            p1 = fmaf(w[1][4 * r4 + 0], hv.x, p1);
            p1 = fmaf(w[1][4 * r4 + 1], hv.y, p1);
            p1 = fmaf(w[1][4 * r4 + 2], hv.z, p1);
            p1 = fmaf(w[1][4 * r4 + 3], hv.w, p1);
            p2 = fmaf(w[2][4 * r4 + 0], hv.x, p2);
            p2 = fmaf(w[2][4 * r4 + 1], hv.y, p2);
            p2 = fmaf(w[2][4 * r4 + 2], hv.z, p2);
            p2 = fmaf(w[2][4 * r4 + 3], hv.w, p2);
            p3 = fmaf(w[3][4 * r4 + 0], hv.x, p3);
            p3 = fmaf(w[3][4 * r4 + 1], hv.y, p3);
            p3 = fmaf(w[3][4 * r4 + 2], hv.z, p3);
            p3 = fmaf(w[3][4 * r4 + 3], hv.w, p3);
        }

        // ---- intra-block k-reduce via LDS (lane-consecutive, 0 conflicts) ----
        red[kg][0][c] = p0;
        red[kg][1][c] = p1;
        red[kg][2][c] = p2;
        red[kg][3][c] = p3;
        __syncthreads();
        float mine = (red[0][kg][c] + red[1][kg][c]) +
                     (red[2][kg][c] + red[3][kg][c]);

        if (!isOwner) {
            // ship tagged partial for col jf to its owner block's mailbox
            unsigned long long pv = ((unsigned long long)tg << 32) |
                                    (unsigned long long)__float_as_uint(mine);
            __hip_atomic_store(&pbuf[(((unsigned)slot * NB + g) * 3 + idx) * HH + jf], pv,
                               __ATOMIC_RELAXED, __HIP_MEMORY_SCOPE_AGENT);
        } else {
            // prefetch next step's xw while partials are in flight
            float xwn = (t + 1 < TT) ? out[(g * TT + t + 1) * HH + jf] : 0.f;
            const unsigned long long* a0 = &pbuf[(((unsigned)slot * NB + g) * 3 + 0) * HH + jf];
            const unsigned long long* a1 = a0 + HH;
            const unsigned long long* a2 = a1 + HH;
            unsigned long long v0, v1, v2;
            do {
                v0 = __hip_atomic_load(a0, __ATOMIC_RELAXED, __HIP_MEMORY_SCOPE_AGENT);
                v1 = __hip_atomic_load(a1, __ATOMIC_RELAXED, __HIP_MEMORY_SCOPE_AGENT);
                v2 = __hip_atomic_load(a2, __ATOMIC_RELAXED, __HIP_MEMORY_SCOPE_AGENT);
            } while ((unsigned)(v0 >> 32) != tg || (unsigned)(v1 >> 32) != tg ||
                     (unsigned)(v2 >> 32) != tg);
            float v = mine + __uint_as_float((unsigned)v0) + __uint_as_float((unsigned)v1) +
                      __uint_as_float((unsigned)v2) + xw;
            // tanh via exp: exact at saturation, ~1e-7 rel error
            float hn = 1.f - 2.f / (__expf(2.f * v) + 1.f);
            out[(g * TT + t) * HH + jf] = hn;
            hsl[(t + 1) & 1][c] = hn;
            xw = xwn;
        }
        __syncthreads();   // hsl[(t+1)&1] + red reuse safe for next iteration
    }
}

// ---------------------------------------------------------------------------
extern "C" void kernel_launch(void* const* d_in, const int* in_sizes, int n_in,
                              void* d_out, int out_size, void* d_ws, size_t ws_size,
                              hipStream_t stream) {
    (void)in_sizes; (void)n_in; (void)out_size; (void)ws_size;
    const float* x  = (const float*)d_in[0];
    const float* h0 = (const float*)d_in[1];
    const float* Wx = (const float*)d_in[2];
    const float* Wh = (const float*)d_in[3];
    const float* bv = (const float*)d_in[4];
    float* out = (float*)d_out;

    // workspace layout
    const size_t PBUF_BYTES = 2ull * NB * 3 * HH * sizeof(unsigned long long); // 1.5 MiB
    unsigned long long* pbuf = (unsigned long long*)d_ws;
    unsigned short* Wt = (unsigned short*)((char*)d_ws + PBUF_BYTES);          // +1 MiB

    // zero mailbox tags (tag 0 never matches any expected tag >= 1)
    hipMemsetAsync(pbuf, 0, PBUF_BYTES, stream);

    // 1) split+transpose Wx -> Wt (bf16 hi|lo, B^T layout)
    wt_kernel<<<64, 256, 0, stream>>>(Wx, Wt);

    // 2) projection GEMM: d_out = x @ Wx + b  (split-bf16 MFMA, fp32-accurate)
    proj_kernel<<<(32768 / 64) * (HH / 64), 256, 0, stream>>>(x, Wt, bv, out);

    // 3) sequential recurrence, partial shipping + conflict-free reduce
    rec_kernel<<<NB * 4, 512, 0, stream>>>(h0, Wh, out, pbuf);
}